// Round 1
// baseline (241.984 us; speedup 1.0000x reference)
//
#include <hip/hip_runtime.h>

#define N_NODES 50000

// ---------------- CSR build ----------------

__global__ void k_hist(const int* __restrict__ dst, int* __restrict__ cnt, int E) {
    int e = blockIdx.x * 256 + threadIdx.x;
    if (e < E) atomicAdd(&cnt[dst[e]], 1);
}

// per-block exclusive scan of 256 elements; block totals to bsum
__global__ void k_scan_a(const int* __restrict__ cnt, int* __restrict__ row_start,
                         int* __restrict__ bsum, int n) {
    __shared__ int sd[256];
    int tid = threadIdx.x;
    int i = blockIdx.x * 256 + tid;
    int v = (i < n) ? cnt[i] : 0;
    sd[tid] = v;
    __syncthreads();
    for (int off = 1; off < 256; off <<= 1) {
        int t = (tid >= off) ? sd[tid - off] : 0;
        __syncthreads();
        sd[tid] += t;
        __syncthreads();
    }
    if (i < n) row_start[i] = sd[tid] - v;   // block-local exclusive
    if (tid == 255) bsum[blockIdx.x] = sd[255];
}

// exclusive scan of block sums (nb <= 256), in place
__global__ void k_scan_b(int* __restrict__ bsum, int nb) {
    __shared__ int sd[256];
    int tid = threadIdx.x;
    int v = (tid < nb) ? bsum[tid] : 0;
    sd[tid] = v;
    __syncthreads();
    for (int off = 1; off < 256; off <<= 1) {
        int t = (tid >= off) ? sd[tid - off] : 0;
        __syncthreads();
        sd[tid] += t;
        __syncthreads();
    }
    if (tid < nb) bsum[tid] = sd[tid] - v;
}

// add block offsets, init cursor, compute dinv = rsqrt(indeg + 1)
__global__ void k_scan_c(const int* __restrict__ cnt, int* __restrict__ row_start,
                         int* __restrict__ cursor, const int* __restrict__ bsum,
                         float* __restrict__ dinv, int n) {
    int i = blockIdx.x * 256 + threadIdx.x;
    if (i < n) {
        int r = row_start[i] + bsum[blockIdx.x];
        row_start[i] = r;
        cursor[i] = r;
        dinv[i] = rsqrtf((float)(cnt[i] + 1));
    }
}

__global__ void k_fill(const int* __restrict__ src, const int* __restrict__ dst,
                       int* __restrict__ cursor, int* __restrict__ eidx, int E) {
    int e = blockIdx.x * 256 + threadIdx.x;
    if (e < E) {
        int pos = atomicAdd(&cursor[dst[e]], 1);
        eidx[pos] = src[e];
    }
}

// ---------------- GEMM 1: h1s[n][j] = dinv[n] * sum_k x[n][k] * W1[k][j] ----------------
// 16 nodes per 256-thread block; x tile + transposed W1 in LDS (stride 132 kills conflicts)

__global__ __launch_bounds__(256) void k_gemm1(const float* __restrict__ x,
                                               const float* __restrict__ W1,
                                               const float* __restrict__ dinv,
                                               float* __restrict__ h1s) {
    __shared__ float sx[16 * 132];
    __shared__ float swT[16 * 132];
    int tid = threadIdx.x;
    int n0 = blockIdx.x * 16;

    // load + transpose W1 [128,16] -> swT[j*132+k]
#pragma unroll
    for (int r = 0; r < 2; r++) {
        int q = tid + 256 * r;                 // float4 index in [0,512)
        float4 v = ((const float4*)W1)[q];
        int k = q >> 2;                        // 0..127
        int j4 = (q & 3) << 2;                 // 0,4,8,12
        swT[(j4 + 0) * 132 + k] = v.x;
        swT[(j4 + 1) * 132 + k] = v.y;
        swT[(j4 + 2) * 132 + k] = v.z;
        swT[(j4 + 3) * 132 + k] = v.w;
    }
    // load x tile: 16 rows x 128 cols
    const float4* x4 = (const float4*)(x + (size_t)n0 * 128);
#pragma unroll
    for (int r = 0; r < 2; r++) {
        int q = tid + 256 * r;
        float4 v = x4[q];
        int node = q >> 5;
        int k = (q & 31) << 2;
        *(float4*)&sx[node * 132 + k] = v;
    }
    __syncthreads();

    int node = tid >> 4;
    int j = tid & 15;
    float acc = 0.f;
#pragma unroll
    for (int k = 0; k < 128; k += 4) {
        float4 a = *(const float4*)&sx[node * 132 + k];
        float4 b = *(const float4*)&swT[j * 132 + k];
        acc = fmaf(a.x, b.x, acc);
        acc = fmaf(a.y, b.y, acc);
        acc = fmaf(a.z, b.z, acc);
        acc = fmaf(a.w, b.w, acc);
    }
    int n = n0 + node;
    h1s[(size_t)n * 16 + j] = dinv[n] * acc;
}

// ---------------- Aggregation: one wave per node ----------------
// lanes: f = lane&15 (feature), sub = lane>>4 (edge subgroup of 4)
// mode 0: z1s = dinv * relu(dinv*acc + b1)      (layer-1 epilogue, pre-scaled for layer 2)
// mode 1: s2  = dinv * acc                       (layer-2 aggregate, bias applied in gemm2)

__global__ __launch_bounds__(256) void k_agg(const float* __restrict__ hin,
                                             const int* __restrict__ row_start,
                                             const int* __restrict__ cnt,
                                             const int* __restrict__ eidx,
                                             const float* __restrict__ dinv,
                                             const float* __restrict__ bias,
                                             float* __restrict__ hout, int mode) {
    int lane = threadIdx.x & 63;
    int node = blockIdx.x * 4 + (threadIdx.x >> 6);   // grid = N/4 exactly
    int f = lane & 15;
    int sub = lane >> 4;

    int start = row_start[node];
    int d = cnt[node];
    float acc = 0.f;
    for (int i = sub; i < d; i += 4) {
        int s = eidx[start + i];
        acc += hin[s * 16 + f];
    }
    acc += __shfl_xor(acc, 16, 64);
    acc += __shfl_xor(acc, 32, 64);
    acc += hin[node * 16 + f];        // self loop (already dinv-scaled)

    float dv = dinv[node];
    float v;
    if (mode == 0) {
        v = fmaxf(dv * acc + bias[f], 0.f) * dv;
    } else {
        v = dv * acc;
    }
    if (sub == 0) hout[node * 16 + f] = v;
}

// ---------------- GEMM 2: out[n][j] = b2[j] + sum_k s2[n][k] * W2[k][j] ----------------
// 16 nodes per 256-thread block; W2 (16x128) in LDS -> 16 regs per thread

__global__ __launch_bounds__(256) void k_gemm2(const float* __restrict__ s2,
                                               const float* __restrict__ W2,
                                               const float* __restrict__ b2,
                                               float* __restrict__ out) {
    __shared__ float sw2[16 * 128];
    __shared__ float ss2[16 * 16];
    int tid = threadIdx.x;
    int n0 = blockIdx.x * 16;

    ((float4*)sw2)[tid] = ((const float4*)W2)[tid];
    ((float4*)sw2)[tid + 256] = ((const float4*)W2)[tid + 256];
    if (tid < 64) ((float4*)ss2)[tid] = ((const float4*)(s2 + (size_t)n0 * 16))[tid];
    __syncthreads();

    int j = tid & 127;
    int half = tid >> 7;
    float w[16];
#pragma unroll
    for (int k = 0; k < 16; k++) w[k] = sw2[k * 128 + j];
    float bj = b2[j];

#pragma unroll
    for (int r = 0; r < 8; r++) {
        int node = half + r * 2;
        float acc = bj;
#pragma unroll
        for (int k = 0; k < 16; k++) acc = fmaf(ss2[node * 16 + k], w[k], acc);
        out[(size_t)(n0 + node) * 128 + j] = acc;
    }
}

// ---------------- launch ----------------

extern "C" void kernel_launch(void* const* d_in, const int* in_sizes, int n_in,
                              void* d_out, int out_size, void* d_ws, size_t ws_size,
                              hipStream_t stream) {
    const float* x  = (const float*)d_in[0];
    const int*   ei = (const int*)d_in[1];
    const float* W1 = (const float*)d_in[2];
    const float* b1 = (const float*)d_in[3];
    const float* W2 = (const float*)d_in[4];
    const float* b2 = (const float*)d_in[5];
    float* out = (float*)d_out;

    const int E = in_sizes[1] / 2;            // 800000
    const int* src = ei;
    const int* dst = ei + E;

    // workspace layout (bytes)
    char* ws = (char*)d_ws;
    int*   cnt       = (int*)(ws + 0);          // 200000 B
    int*   row_start = (int*)(ws + 200000);     // 200000 B
    int*   cursor    = (int*)(ws + 400000);     // 200000 B
    int*   eidx      = (int*)(ws + 600000);     // 3,200,000 B
    float* dinv      = (float*)(ws + 3800000);  // 200000 B
    float* h1s       = (float*)(ws + 4000000);  // 3,200,000 B
    float* z1s       = (float*)(ws + 7200000);  // 3,200,000 B
    float* s2        = h1s;                     // alias: h1s dead after agg1
    int*   bsum      = (int*)(ws + 10400000);   // 1024 B
    // total: ~10.4 MB

    const int NB_N = (N_NODES + 255) / 256;     // 196
    const int NB_E = (E + 255) / 256;           // 3125

    hipMemsetAsync(cnt, 0, N_NODES * sizeof(int), stream);
    k_hist<<<NB_E, 256, 0, stream>>>(dst, cnt, E);
    k_scan_a<<<NB_N, 256, 0, stream>>>(cnt, row_start, bsum, N_NODES);
    k_scan_b<<<1, 256, 0, stream>>>(bsum, NB_N);
    k_scan_c<<<NB_N, 256, 0, stream>>>(cnt, row_start, cursor, bsum, dinv, N_NODES);
    k_fill<<<NB_E, 256, 0, stream>>>(src, dst, cursor, eidx, E);

    k_gemm1<<<N_NODES / 16, 256, 0, stream>>>(x, W1, dinv, h1s);
    k_agg<<<N_NODES / 4, 256, 0, stream>>>(h1s, row_start, cnt, eidx, dinv, b1, z1s, 0);
    k_agg<<<N_NODES / 4, 256, 0, stream>>>(z1s, row_start, cnt, eidx, dinv, b2, s2, 1);
    k_gemm2<<<N_NODES / 16, 256, 0, stream>>>(s2, W2, b2, out);
}